// Round 1
// baseline (661.851 us; speedup 1.0000x reference)
//
#include <hip/hip_runtime.h>
#include <stdint.h>

#define CBP_D 8192
#define CBP_C 512
#define CBP_W 512
#define ROWS 8
#define LSTRIDE 10   // floats per channel-row in LDS (8 used + 2 pad => 40B stride)
#define NSPLIT 4
#define NTHREADS 256

// ---------------- precompute: deterministic CSR pair list ----------------

__global__ void k_count2(const int* __restrict__ h2, int* __restrict__ cnt2) {
    int t = blockIdx.x * blockDim.x + threadIdx.x;   // 0..8191
    int c = 0;
    for (int j = 0; j < CBP_C; ++j) c += (h2[j] == t);
    cnt2[t] = c;
}

// exclusive scan of 8192 ints -> out[0..8192]
__global__ void k_scan8192(const int* __restrict__ in, int* __restrict__ out) {
    __shared__ int sm[1024];
    int t = threadIdx.x;
    int v[8]; int sum = 0;
#pragma unroll
    for (int k = 0; k < 8; ++k) { v[k] = in[t * 8 + k]; sum += v[k]; }
    sm[t] = sum; __syncthreads();
    int acc = sum;
    for (int off = 1; off < 1024; off <<= 1) {
        int add = (t >= off) ? sm[t - off] : 0;
        __syncthreads();
        acc += add; sm[t] = acc;
        __syncthreads();
    }
    int excl = acc - sum;
#pragma unroll
    for (int k = 0; k < 8; ++k) { out[t * 8 + k] = excl; excl += v[k]; }
    if (t == 1023) out[8192] = excl;
}

__global__ void k_fill_bucket2(const int* __restrict__ h2, const int* __restrict__ boff,
                               int* __restrict__ bucket2) {
    int t = blockIdx.x * blockDim.x + threadIdx.x;
    int k = boff[t];
    for (int j = 0; j < CBP_C; ++j) if (h2[j] == t) bucket2[k++] = j;
}

__global__ void k_countd(const int* __restrict__ h1, const int* __restrict__ cnt2,
                         int* __restrict__ cnt) {
    int d = blockIdx.x * blockDim.x + threadIdx.x;
    int n = 0;
    for (int i = 0; i < CBP_C; ++i) {
        int t = (d - h1[i]) & (CBP_D - 1);
        n += cnt2[t];
    }
    cnt[d] = n;
}

__global__ void k_fill_pairs(const int* __restrict__ h1, const int* __restrict__ cnt2,
                             const int* __restrict__ boff, const int* __restrict__ bucket2,
                             const int* __restrict__ offs, uint32_t* __restrict__ pairs) {
    int d = blockIdx.x * blockDim.x + threadIdx.x;
    int pos = offs[d];
    for (int i = 0; i < CBP_C; ++i) {
        int t = (d - h1[i]) & (CBP_D - 1);
        int n = cnt2[t], bo = boff[t];
        for (int k = 0; k < n; ++k)
            pairs[pos++] = (uint32_t)i | ((uint32_t)bucket2[bo + k] << 9);
    }
}

// ---------------- main: gather-accumulate ----------------

#define PROC(p) { \
    int i_ = (int)((p) & 511u); int j_ = (int)(((p) >> 9) & 511u); \
    const float2* qa = (const float2*)&x1T[i_ * LSTRIDE]; \
    const float2* qb = (const float2*)&x2T[j_ * LSTRIDE]; \
    float2 a0 = qa[0], a1 = qa[1], a2 = qa[2], a3 = qa[3]; \
    float2 c0 = qb[0], c1 = qb[1], c2 = qb[2], c3 = qb[3]; \
    acc0 += a0.x * c0.x; acc1 += a0.y * c0.y; \
    acc2 += a1.x * c1.x; acc3 += a1.y * c1.y; \
    acc4 += a2.x * c2.x; acc5 += a2.y * c2.y; \
    acc6 += a3.x * c3.x; acc7 += a3.y * c3.y; }

__global__ __launch_bounds__(NTHREADS, 4)
void k_main(const float* __restrict__ b1, const float* __restrict__ b2,
            const float* __restrict__ s1, const float* __restrict__ s2,
            const int* __restrict__ offs, const uint32_t* __restrict__ pairs,
            float* __restrict__ out) {
    __shared__ float x1T[CBP_C * LSTRIDE];   // 20 KB
    __shared__ float x2T[CBP_C * LSTRIDE];   // 20 KB
    int bx = blockIdx.x;                     // 512 row-blocks
    int gy = blockIdx.y;                     // NSPLIT d-splits
    int r_base = bx * ROWS;
    int b = r_base >> 9;                     // W=512 rows per batch image
    int w0 = r_base & (CBP_W - 1);
    int tid = threadIdx.x;

    // stage 8 rows of sign-folded x1, x2, transposed: xT[c][r]
    for (int c = tid; c < CBP_C; c += NTHREADS) {
        const float* p1 = b1 + ((size_t)b * CBP_C + c) * CBP_W + w0;
        const float* p2 = b2 + ((size_t)b * CBP_C + c) * CBP_W + w0;
        float4 u0 = *(const float4*)p1, u1 = *(const float4*)(p1 + 4);
        float4 v0 = *(const float4*)p2, v1 = *(const float4*)(p2 + 4);
        float sa = s1[c], sb = s2[c];
        float* d1 = &x1T[c * LSTRIDE];
        float* d2 = &x2T[c * LSTRIDE];
        d1[0] = u0.x * sa; d1[1] = u0.y * sa; d1[2] = u0.z * sa; d1[3] = u0.w * sa;
        d1[4] = u1.x * sa; d1[5] = u1.y * sa; d1[6] = u1.z * sa; d1[7] = u1.w * sa;
        d2[0] = v0.x * sb; d2[1] = v0.y * sb; d2[2] = v0.z * sb; d2[3] = v0.w * sb;
        d2[4] = v1.x * sb; d2[5] = v1.y * sb; d2[6] = v1.z * sb; d2[7] = v1.w * sb;
    }
    __syncthreads();

    const int DSEG = CBP_D / NSPLIT;         // 2048
    for (int it = 0; it < DSEG / NTHREADS; ++it) {   // 8 iters
        int d = gy * DSEG + it * NTHREADS + tid;
        int off = offs[d];
        int n = offs[d + 1] - off;
        float acc0 = 0, acc1 = 0, acc2 = 0, acc3 = 0;
        float acc4 = 0, acc5 = 0, acc6 = 0, acc7 = 0;
        int e = 0;
        for (; e + 4 <= n; e += 4) {
            uint32_t p0 = pairs[off + e];
            uint32_t p1 = pairs[off + e + 1];
            uint32_t p2 = pairs[off + e + 2];
            uint32_t p3 = pairs[off + e + 3];
            PROC(p0); PROC(p1); PROC(p2); PROC(p3);
        }
        for (; e < n; ++e) { uint32_t p = pairs[off + e]; PROC(p); }
        float* o = out + (size_t)r_base * CBP_D + d;
        o[0 * CBP_D] = acc0; o[1 * CBP_D] = acc1; o[2 * CBP_D] = acc2; o[3 * CBP_D] = acc3;
        o[4 * CBP_D] = acc4; o[5 * CBP_D] = acc5; o[6 * CBP_D] = acc6; o[7 * CBP_D] = acc7;
    }
}

// ---------------- launch ----------------

extern "C" void kernel_launch(void* const* d_in, const int* in_sizes, int n_in,
                              void* d_out, int out_size, void* d_ws, size_t ws_size,
                              hipStream_t stream) {
    const float* b1 = (const float*)d_in[0];
    const float* b2 = (const float*)d_in[1];
    const int*   h1 = (const int*)d_in[2];
    const float* s1 = (const float*)d_in[3];
    const int*   h2 = (const int*)d_in[4];
    const float* s2 = (const float*)d_in[5];
    float* out = (float*)d_out;

    int* cnt2    = (int*)d_ws;          // 8192
    int* boff    = cnt2 + 8192;         // 8193
    int* bucket2 = boff + 8193;         // 512
    int* cnt     = bucket2 + 512;       // 8192
    int* offs    = cnt + 8192;          // 8193
    uint32_t* pairs = (uint32_t*)(offs + 8193);   // 262144

    k_count2<<<32, 256, 0, stream>>>(h2, cnt2);
    k_scan8192<<<1, 1024, 0, stream>>>(cnt2, boff);
    k_fill_bucket2<<<32, 256, 0, stream>>>(h2, boff, bucket2);
    k_countd<<<32, 256, 0, stream>>>(h1, cnt2, cnt);
    k_scan8192<<<1, 1024, 0, stream>>>(cnt, offs);
    k_fill_pairs<<<32, 256, 0, stream>>>(h1, cnt2, boff, bucket2, offs, pairs);

    dim3 grid(CBP_W * CBP_D / CBP_D /*keep simple*/ , 1, 1);
    (void)grid;
    dim3 g((4096 / ROWS), NSPLIT);      // 512 x 4
    k_main<<<g, NTHREADS, 0, stream>>>(b1, b2, s1, s2, offs, pairs, out);
}

// Round 2
// 497.688 us; speedup vs baseline: 1.3299x; 1.3299x over previous
//
#include <hip/hip_runtime.h>
#include <stdint.h>

#define CBP_D 8192
#define CBP_C 512
#define CBP_W 512
#define ROWS 32          // rows staged per block (= lanes per half-wave)
#define NTHREADS 1024    // 16 waves
#define NSPLIT 2         // d-range splits (128 row-blocks x 2 = 256 blocks)

// ================= precompute =================

// P1: single block. cnt2 (histogram of h2), boff (exclusive scan), bucket2
// (j's grouped by target bucket, deterministic order via rank).
__global__ void p1_buckets(const int* __restrict__ h2, int* __restrict__ cnt2_g,
                           int* __restrict__ boff_g, int* __restrict__ bucket2_g) {
    __shared__ int scnt[CBP_D];     // histogram, then reused as boff
    __shared__ int sh2[CBP_C];
    __shared__ int ssum[512];
    int t = threadIdx.x;            // 512 threads
    for (int k = t; k < CBP_D; k += 512) scnt[k] = 0;
    sh2[t] = h2[t];
    __syncthreads();
    atomicAdd(&scnt[sh2[t]], 1);    // counts: order-independent -> deterministic
    __syncthreads();
    // save histogram to global, keep local copy of this thread's 16 elems
    int base = t * 16;
    int loc[16]; int s = 0;
#pragma unroll
    for (int k = 0; k < 16; ++k) { loc[k] = scnt[base + k]; cnt2_g[base + k] = loc[k]; s += loc[k]; }
    ssum[t] = s;
    __syncthreads();
    int acc = s;
    for (int off = 1; off < 512; off <<= 1) {
        int add = (t >= off) ? ssum[t - off] : 0;
        __syncthreads();
        acc += add; ssum[t] = acc;
        __syncthreads();
    }
    int excl = acc - s;
    // write boff into global AND back into scnt (reused as LDS boff)
#pragma unroll
    for (int k = 0; k < 16; ++k) { boff_g[base + k] = excl; scnt[base + k] = excl; excl += loc[k]; }
    if (t == 511) boff_g[CBP_D] = excl;
    __syncthreads();
    // deterministic scatter: rank of j among equal h2 values
    int h = sh2[t]; int r = 0;
    for (int j2 = 0; j2 < t; ++j2) r += (sh2[j2] == h);
    bucket2_g[scnt[h] + r] = t;
}

// P2: per-d pair counts. cnt[d] = sum_i cnt2[(d - h1[i]) mod D]
__global__ void p2_countd(const int* __restrict__ h1, const int* __restrict__ cnt2,
                          int* __restrict__ cnt) {
    __shared__ int sc[CBP_D];       // 32 KB
    __shared__ int sh1[CBP_C];
    int tid = threadIdx.x;          // 128
    for (int k = tid; k < CBP_D; k += 128) sc[k] = cnt2[k];
    for (int k = tid; k < CBP_C; k += 128) sh1[k] = h1[k];
    __syncthreads();
    int d = blockIdx.x * 128 + tid;
    int n = 0;
#pragma unroll 4
    for (int i = 0; i < CBP_C; ++i) n += sc[(d - sh1[i]) & (CBP_D - 1)];
    cnt[d] = n;
}

// P3: exclusive scan of 8192 counts, each padded up to multiple of 4
// (so every d's pair list is uint4-aligned).
__global__ void p3_scan_pad(const int* __restrict__ in, int* __restrict__ out) {
    __shared__ int sm[1024];
    int t = threadIdx.x;
    int v[8]; int sum = 0;
#pragma unroll
    for (int k = 0; k < 8; ++k) { v[k] = (in[t * 8 + k] + 3) & ~3; sum += v[k]; }
    sm[t] = sum; __syncthreads();
    int acc = sum;
    for (int off = 1; off < 1024; off <<= 1) {
        int add = (t >= off) ? sm[t - off] : 0;
        __syncthreads();
        acc += add; sm[t] = acc;
        __syncthreads();
    }
    int excl = acc - sum;
#pragma unroll
    for (int k = 0; k < 8; ++k) { out[t * 8 + k] = excl; excl += v[k]; }
    if (t == 1023) out[CBP_D] = excl;
}

// P4: emit pair words: (i*32) | (j*32 << 16)  == packed LDS float-indices.
__global__ void p4_fill(const int* __restrict__ h1, const int* __restrict__ cnt2,
                        const int* __restrict__ boff, const int* __restrict__ bucket2,
                        const int* __restrict__ offs, uint32_t* __restrict__ pairs) {
    __shared__ int sc[CBP_D];       // 32 KB
    __shared__ int sb[CBP_D];       // 32 KB
    __shared__ short sbk[CBP_C];
    __shared__ int sh1[CBP_C];
    int tid = threadIdx.x;          // 128
    for (int k = tid; k < CBP_D; k += 128) { sc[k] = cnt2[k]; sb[k] = boff[k]; }
    for (int k = tid; k < CBP_C; k += 128) { sbk[k] = (short)bucket2[k]; sh1[k] = h1[k]; }
    __syncthreads();
    int d = blockIdx.x * 128 + tid;
    int pos = offs[d];
    for (int i = 0; i < CBP_C; ++i) {
        int t = (d - sh1[i]) & (CBP_D - 1);
        int n = sc[t];
        if (n) {
            int bo = sb[t];
            uint32_t iw = (uint32_t)(i << 5);
            for (int k = 0; k < n; ++k)
                pairs[pos++] = iw | ((uint32_t)sbk[bo + k] << 21);
        }
    }
}

// ================= main =================

#define MAC1(P) { \
    float av = a0[(P) & 0xFFFFu]; \
    float bv = b0[(P) >> 16]; \
    acc = fmaf(av, bv, acc); }

__global__ __launch_bounds__(NTHREADS, 1)
void k_main(const float* __restrict__ b1, const float* __restrict__ b2,
            const float* __restrict__ s1, const float* __restrict__ s2,
            const int* __restrict__ offs, const int* __restrict__ cnt,
            const uint32_t* __restrict__ pairs, float* __restrict__ out) {
    __shared__ float x1T[CBP_C * ROWS];   // 64 KB  [c][r]
    __shared__ float x2T[CBP_C * ROWS];   // 64 KB
    int bx = blockIdx.x;                  // 0..127 row-block
    int gy = blockIdx.y;                  // 0..NSPLIT-1
    int r_base = bx * ROWS;
    int b = r_base >> 9;
    int w0 = r_base & (CBP_W - 1);
    int tid = threadIdx.x;

    // stage sign-folded transposed rows: x[c][r], fp32
    for (int idx = tid; idx < CBP_C * ROWS / 4; idx += NTHREADS) {
        int c = idx >> 3;
        int r4 = (idx & 7) << 2;
        size_t g = ((size_t)(b * CBP_C + c)) * CBP_W + w0 + r4;
        float4 u = *(const float4*)(b1 + g);
        float4 v = *(const float4*)(b2 + g);
        float sa = s1[c], sb = s2[c];
        *(float4*)&x1T[(c << 5) + r4] = make_float4(u.x * sa, u.y * sa, u.z * sa, u.w * sa);
        *(float4*)&x2T[(c << 5) + r4] = make_float4(v.x * sb, v.y * sb, v.z * sb, v.w * sb);
    }
    __syncthreads();

    int wv = tid >> 6;                    // 0..15
    int lane = tid & 63;
    int half = lane >> 5;                 // two d-streams per wave
    int l = lane & 31;                    // row within block
    const float* a0 = x1T + l;
    const float* b0 = x2T + l;
    int dbase = gy * (CBP_D / NSPLIT) + wv * 256;
    float* orow = out + (size_t)(r_base + l) * CBP_D;

    for (int dd = 0; dd < 128; ++dd) {
        int d = dbase + (dd << 1) + half;
        int off = offs[d];                // uint4-aligned
        int n = cnt[d];
        const uint4* pl4 = (const uint4*)(pairs + off);
        float acc = 0.f;
        int nb = n >> 2;
        if (nb > 0) {
            uint4 pp = pl4[0];
            for (int t4 = 0; t4 < nb; ++t4) {
                int nxt = (t4 + 1 < nb) ? t4 + 1 : t4;
                uint4 nx = pl4[nxt];      // 1-deep prefetch, clamped
                MAC1(pp.x); MAC1(pp.y); MAC1(pp.z); MAC1(pp.w);
                pp = nx;
            }
        }
        for (int e = n & ~3; e < n; ++e) {
            uint32_t p = pairs[off + e];
            MAC1(p);
        }
        orow[d] = acc;
    }
}

// ================= launch =================

extern "C" void kernel_launch(void* const* d_in, const int* in_sizes, int n_in,
                              void* d_out, int out_size, void* d_ws, size_t ws_size,
                              hipStream_t stream) {
    const float* b1 = (const float*)d_in[0];
    const float* b2 = (const float*)d_in[1];
    const int*   h1 = (const int*)d_in[2];
    const float* s1 = (const float*)d_in[3];
    const int*   h2 = (const int*)d_in[4];
    const float* s2 = (const float*)d_in[5];
    float* out = (float*)d_out;

    int* cnt2    = (int*)d_ws;            // 8192
    int* boff    = cnt2 + 8192;           // 8200 (8193 used)
    int* bucket2 = boff + 8200;           // 512
    int* cnt     = bucket2 + 512;         // 8192
    int* offs    = cnt + 8192;            // 8200 (8193 used)
    uint32_t* pairs = (uint32_t*)(offs + 8200);   // <= 262144 + 3*8192 + pad

    p1_buckets<<<1, 512, 0, stream>>>(h2, cnt2, boff, bucket2);
    p2_countd <<<64, 128, 0, stream>>>(h1, cnt2, cnt);
    p3_scan_pad<<<1, 1024, 0, stream>>>(cnt, offs);
    p4_fill   <<<64, 128, 0, stream>>>(h1, cnt2, boff, bucket2, offs, pairs);

    dim3 g(CBP_W * 8 / ROWS, NSPLIT);     // (128, 2)
    k_main<<<g, NTHREADS, 0, stream>>>(b1, b2, s1, s2, offs, cnt, pairs, out);
}

// Round 3
// 402.598 us; speedup vs baseline: 1.6440x; 1.2362x over previous
//
#include <hip/hip_runtime.h>
#include <hip/hip_fp16.h>
#include <stdint.h>

#define CBP_D 8192
#define CBP_C 512
#define CBP_W 512
#define ROWS 64          // rows staged per block; lane covers 2 rows via __half2
#define NTHREADS 1024    // 16 waves
#define NSPLIT 4         // d-range splits -> 64 x 4 = 256 blocks = 1/CU

// ================= precompute =================

// P1: single block. cnt2 (histogram of h2), boff (exclusive scan), bucket2
// (j's grouped by target bucket, deterministic order via rank).
__global__ void p1_buckets(const int* __restrict__ h2, int* __restrict__ cnt2_g,
                           int* __restrict__ boff_g, int* __restrict__ bucket2_g) {
    __shared__ int scnt[CBP_D];
    __shared__ int sh2[CBP_C];
    __shared__ int ssum[512];
    int t = threadIdx.x;            // 512 threads
    for (int k = t; k < CBP_D; k += 512) scnt[k] = 0;
    sh2[t] = h2[t];
    __syncthreads();
    atomicAdd(&scnt[sh2[t]], 1);
    __syncthreads();
    int base = t * 16;
    int loc[16]; int s = 0;
#pragma unroll
    for (int k = 0; k < 16; ++k) { loc[k] = scnt[base + k]; cnt2_g[base + k] = loc[k]; s += loc[k]; }
    ssum[t] = s;
    __syncthreads();
    int acc = s;
    for (int off = 1; off < 512; off <<= 1) {
        int add = (t >= off) ? ssum[t - off] : 0;
        __syncthreads();
        acc += add; ssum[t] = acc;
        __syncthreads();
    }
    int excl = acc - s;
#pragma unroll
    for (int k = 0; k < 16; ++k) { boff_g[base + k] = excl; scnt[base + k] = excl; excl += loc[k]; }
    if (t == 511) boff_g[CBP_D] = excl;
    __syncthreads();
    int h = sh2[t]; int r = 0;
    for (int j2 = 0; j2 < t; ++j2) r += (sh2[j2] == h);
    bucket2_g[scnt[h] + r] = t;
}

// P2: per-d pair counts. cnt[d] = sum_i cnt2[(d - h1[i]) mod D]
__global__ void p2_countd(const int* __restrict__ h1, const int* __restrict__ cnt2,
                          int* __restrict__ cnt) {
    __shared__ int sc[CBP_D];
    __shared__ int sh1[CBP_C];
    int tid = threadIdx.x;          // 128
    for (int k = tid; k < CBP_D; k += 128) sc[k] = cnt2[k];
    for (int k = tid; k < CBP_C; k += 128) sh1[k] = h1[k];
    __syncthreads();
    int d = blockIdx.x * 128 + tid;
    int n = 0;
#pragma unroll 4
    for (int i = 0; i < CBP_C; ++i) n += sc[(d - sh1[i]) & (CBP_D - 1)];
    cnt[d] = n;
}

// P3: exclusive scan of 8192 counts, each padded up to multiple of 4.
__global__ void p3_scan_pad(const int* __restrict__ in, int* __restrict__ out) {
    __shared__ int sm[1024];
    int t = threadIdx.x;
    int v[8]; int sum = 0;
#pragma unroll
    for (int k = 0; k < 8; ++k) { v[k] = (in[t * 8 + k] + 3) & ~3; sum += v[k]; }
    sm[t] = sum; __syncthreads();
    int acc = sum;
    for (int off = 1; off < 1024; off <<= 1) {
        int add = (t >= off) ? sm[t - off] : 0;
        __syncthreads();
        acc += add; sm[t] = acc;
        __syncthreads();
    }
    int excl = acc - sum;
#pragma unroll
    for (int k = 0; k < 8; ++k) { out[t * 8 + k] = excl; excl += v[k]; }
    if (t == 1023) out[CBP_D] = excl;
}

// P4: emit pair words: i | (j << 16)  (plain indices; kernel shifts <<7).
__global__ void p4_fill(const int* __restrict__ h1, const int* __restrict__ cnt2,
                        const int* __restrict__ boff, const int* __restrict__ bucket2,
                        const int* __restrict__ offs, uint32_t* __restrict__ pairs) {
    __shared__ int sc[CBP_D];
    __shared__ int sb[CBP_D];
    __shared__ short sbk[CBP_C];
    __shared__ int sh1[CBP_C];
    int tid = threadIdx.x;          // 128
    for (int k = tid; k < CBP_D; k += 128) { sc[k] = cnt2[k]; sb[k] = boff[k]; }
    for (int k = tid; k < CBP_C; k += 128) { sbk[k] = (short)bucket2[k]; sh1[k] = h1[k]; }
    __syncthreads();
    int d = blockIdx.x * 128 + tid;
    int pos = offs[d];
    for (int i = 0; i < CBP_C; ++i) {
        int t = (d - sh1[i]) & (CBP_D - 1);
        int n = sc[t];
        if (n) {
            int bo = sb[t];
            uint32_t iw = (uint32_t)i;
            for (int k = 0; k < n; ++k)
                pairs[pos++] = iw | ((uint32_t)sbk[bo + k] << 16);
        }
    }
}

// ================= main =================

// lane covers rows 2l, 2l+1 (one __half2 per operand per entry)
#define PROC(P) { \
    uint32_t p_ = (P); \
    __half2 av_ = *(const __half2*)(aBase + ((p_ & 0xFFFFu) << 7)); \
    __half2 bv_ = *(const __half2*)(bBase + ((p_ >> 16) << 7)); \
    float2 af_ = __half22float2(av_); \
    float2 bf_ = __half22float2(bv_); \
    ax = fmaf(af_.x, bf_.x, ax); \
    ay = fmaf(af_.y, bf_.y, ay); }

__global__ __launch_bounds__(NTHREADS, 1)
void k_main(const float* __restrict__ b1, const float* __restrict__ b2,
            const float* __restrict__ s1, const float* __restrict__ s2,
            const int* __restrict__ offs, const int* __restrict__ cnt,
            const uint32_t* __restrict__ pairs, float* __restrict__ out) {
    __shared__ __half x1h[CBP_C * ROWS];   // 64 KB  [c][r] f16, sign-folded
    __shared__ __half x2h[CBP_C * ROWS];   // 64 KB
    int bx = blockIdx.x;                   // 0..63 row-block
    int gy = blockIdx.y;                   // 0..3
    int r_base = bx * ROWS;
    int b = r_base >> 9;
    int w0 = r_base & (CBP_W - 1);
    int tid = threadIdx.x;

    // stage: unit = (c, group of 8 rows); 4096 units / 1024 threads
    for (int u = tid; u < CBP_C * 8; u += NTHREADS) {
        int c = u >> 3;
        int r8 = (u & 7) << 3;             // element offset within row
        size_t g = ((size_t)(b * CBP_C + c)) * CBP_W + w0 + r8;
        float4 u0 = *(const float4*)(b1 + g), u1 = *(const float4*)(b1 + g + 4);
        float4 v0 = *(const float4*)(b2 + g), v1 = *(const float4*)(b2 + g + 4);
        float sa = s1[c], sb = s2[c];
        union { __half2 h2[4]; uint4 q; } A, Bv;
        A.h2[0] = __floats2half2_rn(u0.x * sa, u0.y * sa);
        A.h2[1] = __floats2half2_rn(u0.z * sa, u0.w * sa);
        A.h2[2] = __floats2half2_rn(u1.x * sa, u1.y * sa);
        A.h2[3] = __floats2half2_rn(u1.z * sa, u1.w * sa);
        Bv.h2[0] = __floats2half2_rn(v0.x * sb, v0.y * sb);
        Bv.h2[1] = __floats2half2_rn(v0.z * sb, v0.w * sb);
        Bv.h2[2] = __floats2half2_rn(v1.x * sb, v1.y * sb);
        Bv.h2[3] = __floats2half2_rn(v1.z * sb, v1.w * sb);
        *(uint4*)&x1h[(c << 6) + r8] = A.q;
        *(uint4*)&x2h[(c << 6) + r8] = Bv.q;
    }
    __syncthreads();

    int wv = tid >> 6;                     // 0..15
    int lane = tid & 63;
    int half_ = lane >> 5;                 // two d-streams per wave
    int l = lane & 31;                     // covers rows 2l, 2l+1
    const char* aBase = (const char*)x1h + l * 4;
    const char* bBase = (const char*)x2h + l * 4;
    int dbase = gy * (CBP_D / NSPLIT) + wv * 128;
    float* orow0 = out + (size_t)(r_base + 2 * l) * CBP_D;
    float* orow1 = orow0 + CBP_D;

    for (int dd = 0; dd < 64; ++dd) {
        int d = dbase + (dd << 1) + half_;
        int o0 = offs[d];                  // uint4-aligned
        int n = cnt[d];
        const uint4* pl = (const uint4*)(pairs + o0);
        float ax = 0.f, ay = 0.f;
        int nb = n >> 2;
        for (int t4 = 0; t4 < nb; ++t4) {
            uint4 pp = pl[t4];
            PROC(pp.x); PROC(pp.y); PROC(pp.z); PROC(pp.w);
        }
        for (int e = n & ~3; e < n; ++e) {
            uint32_t p = pairs[o0 + e];
            PROC(p);
        }
        orow0[d] = ax;
        orow1[d] = ay;
    }
}

// ================= launch =================

extern "C" void kernel_launch(void* const* d_in, const int* in_sizes, int n_in,
                              void* d_out, int out_size, void* d_ws, size_t ws_size,
                              hipStream_t stream) {
    const float* b1 = (const float*)d_in[0];
    const float* b2 = (const float*)d_in[1];
    const int*   h1 = (const int*)d_in[2];
    const float* s1 = (const float*)d_in[3];
    const int*   h2 = (const int*)d_in[4];
    const float* s2 = (const float*)d_in[5];
    float* out = (float*)d_out;

    int* cnt2    = (int*)d_ws;            // 8192
    int* boff    = cnt2 + 8192;           // 8200 (8193 used)
    int* bucket2 = boff + 8200;           // 512
    int* cnt     = bucket2 + 512;         // 8192
    int* offs    = cnt + 8192;            // 8200 (8193 used)
    uint32_t* pairs = (uint32_t*)(offs + 8200);   // <= 262144 + 3*8192

    p1_buckets<<<1, 512, 0, stream>>>(h2, cnt2, boff, bucket2);
    p2_countd <<<64, 128, 0, stream>>>(h1, cnt2, cnt);
    p3_scan_pad<<<1, 1024, 0, stream>>>(cnt, offs);
    p4_fill   <<<64, 128, 0, stream>>>(h1, cnt2, boff, bucket2, offs, pairs);

    dim3 g(CBP_W * 8 / ROWS, NSPLIT);     // (64, 4)
    k_main<<<g, NTHREADS, 0, stream>>>(b1, b2, s1, s2, offs, cnt, pairs, out);
}

// Round 4
// 327.213 us; speedup vs baseline: 2.0227x; 1.2304x over previous
//
#include <hip/hip_runtime.h>
#include <hip/hip_fp16.h>
#include <stdint.h>

#define CBP_D 8192
#define CBP_C 512
#define CBP_W 512
#define ROWS 64          // rows staged per block; lane covers 4 rows via ds_read_b64
#define NTHREADS 1024    // 16 waves
#define NSPLIT 4         // 64 row-blocks x 4 = 256 blocks = 1/CU

// LDS layout (bytes): x2 rows 0..512 (513*128, row 512 = zeros), then x1 rows 0..511
#define X1OFF 65664
#define PADW  (512u << 17)   // pad pair word: j=512 (zero row), i=0

// ================= precompute =================

__global__ void p1_buckets(const int* __restrict__ h2, int* __restrict__ cnt2_g,
                           int* __restrict__ boff_g, int* __restrict__ bucket2_g) {
    __shared__ int scnt[CBP_D];
    __shared__ int sh2[CBP_C];
    __shared__ int ssum[512];
    int t = threadIdx.x;            // 512 threads
    for (int k = t; k < CBP_D; k += 512) scnt[k] = 0;
    sh2[t] = h2[t];
    __syncthreads();
    atomicAdd(&scnt[sh2[t]], 1);
    __syncthreads();
    int base = t * 16;
    int loc[16]; int s = 0;
#pragma unroll
    for (int k = 0; k < 16; ++k) { loc[k] = scnt[base + k]; cnt2_g[base + k] = loc[k]; s += loc[k]; }
    ssum[t] = s;
    __syncthreads();
    int acc = s;
    for (int off = 1; off < 512; off <<= 1) {
        int add = (t >= off) ? ssum[t - off] : 0;
        __syncthreads();
        acc += add; ssum[t] = acc;
        __syncthreads();
    }
    int excl = acc - s;
#pragma unroll
    for (int k = 0; k < 16; ++k) { boff_g[base + k] = excl; scnt[base + k] = excl; excl += loc[k]; }
    if (t == 511) boff_g[CBP_D] = excl;
    __syncthreads();
    int h = sh2[t]; int r = 0;
    for (int j2 = 0; j2 < t; ++j2) r += (sh2[j2] == h);
    bucket2_g[scnt[h] + r] = t;
}

__global__ void p2_countd(const int* __restrict__ h1, const int* __restrict__ cnt2,
                          int* __restrict__ cnt) {
    __shared__ int sc[CBP_D];
    __shared__ int sh1[CBP_C];
    int tid = threadIdx.x;          // 128
    for (int k = tid; k < CBP_D; k += 128) sc[k] = cnt2[k];
    for (int k = tid; k < CBP_C; k += 128) sh1[k] = h1[k];
    __syncthreads();
    int d = blockIdx.x * 128 + tid;
    int n = 0;
#pragma unroll 4
    for (int i = 0; i < CBP_C; ++i) n += sc[(d - sh1[i]) & (CBP_D - 1)];
    cnt[d] = n;
}

// exclusive scan of counts padded to multiples of 4
__global__ void p3_scan_pad(const int* __restrict__ in, int* __restrict__ out) {
    __shared__ int sm[1024];
    int t = threadIdx.x;
    int v[8]; int sum = 0;
#pragma unroll
    for (int k = 0; k < 8; ++k) { v[k] = (in[t * 8 + k] + 3) & ~3; sum += v[k]; }
    sm[t] = sum; __syncthreads();
    int acc = sum;
    for (int off = 1; off < 1024; off <<= 1) {
        int add = (t >= off) ? sm[t - off] : 0;
        __syncthreads();
        acc += add; sm[t] = acc;
        __syncthreads();
    }
    int excl = acc - sum;
#pragma unroll
    for (int k = 0; k < 8; ++k) { out[t * 8 + k] = excl; excl += v[k]; }
    if (t == 1023) out[CBP_D] = excl;
}

// pair word = (i<<7) | (j<<17); pad slots = PADW (hits staged zero row)
__global__ void p4_fill(const int* __restrict__ h1, const int* __restrict__ cnt2,
                        const int* __restrict__ boff, const int* __restrict__ bucket2,
                        const int* __restrict__ offs, uint32_t* __restrict__ pairs) {
    __shared__ int sc[CBP_D];
    __shared__ int sb[CBP_D];
    __shared__ short sbk[CBP_C];
    __shared__ int sh1[CBP_C];
    int tid = threadIdx.x;          // 128
    for (int k = tid; k < CBP_D; k += 128) { sc[k] = cnt2[k]; sb[k] = boff[k]; }
    for (int k = tid; k < CBP_C; k += 128) { sbk[k] = (short)bucket2[k]; sh1[k] = h1[k]; }
    __syncthreads();
    int d = blockIdx.x * 128 + tid;
    int pos = offs[d];
    int end = offs[d + 1];
    for (int i = 0; i < CBP_C; ++i) {
        int t = (d - sh1[i]) & (CBP_D - 1);
        int n = sc[t];
        if (n) {
            int bo = sb[t];
            uint32_t iw = (uint32_t)(i << 7);
            for (int k = 0; k < n; ++k)
                pairs[pos++] = iw | ((uint32_t)sbk[bo + k] << 17);
        }
    }
    for (; pos < end; ++pos) pairs[pos] = PADW;
}

// ================= main =================

#define PROC(P) { \
    uint32_t p_ = (P); \
    uint32_t aB_ = (p_ & 0x1FF80u) + baseA; \
    uint32_t bB_ = ((p_ >> 10) & 0x1FF80u) | baseB; \
    uint2 ra_ = *(const uint2*)(xsh + aB_); \
    uint2 rb_ = *(const uint2*)(xsh + bB_); \
    __half2 ah0_ = *(const __half2*)&ra_.x, ah1_ = *(const __half2*)&ra_.y; \
    __half2 bh0_ = *(const __half2*)&rb_.x, bh1_ = *(const __half2*)&rb_.y; \
    ac0 = fmaf(__low2float(ah0_),  __low2float(bh0_),  ac0); \
    ac1 = fmaf(__high2float(ah0_), __high2float(bh0_), ac1); \
    ac2 = fmaf(__low2float(ah1_),  __low2float(bh1_),  ac2); \
    ac3 = fmaf(__high2float(ah1_), __high2float(bh1_), ac3); }

__global__ __launch_bounds__(NTHREADS, 1)
void k_main(const float* __restrict__ b1, const float* __restrict__ b2,
            const float* __restrict__ s1, const float* __restrict__ s2,
            const int* __restrict__ offs, const uint32_t* __restrict__ pairs,
            float* __restrict__ out) {
    __shared__ __align__(16) char xsh[131200];   // x2 (513 rows incl. zero row) + x1 (512 rows)
    int bx = blockIdx.x;                   // 0..63 row-block
    int gy = blockIdx.y;                   // 0..3
    int r_base = bx * ROWS;
    int b = r_base >> 9;
    int w0 = r_base & (CBP_W - 1);
    int tid = threadIdx.x;

    // stage sign-folded f16, transposed [c][r]; x2 first, x1 at X1OFF
    for (int u = tid; u < CBP_C * 8; u += NTHREADS) {
        int c = u >> 3;
        int r8 = (u & 7) << 3;             // element offset within row
        size_t g = ((size_t)(b * CBP_C + c)) * CBP_W + w0 + r8;
        float4 u0 = *(const float4*)(b1 + g), u1 = *(const float4*)(b1 + g + 4);
        float4 v0 = *(const float4*)(b2 + g), v1 = *(const float4*)(b2 + g + 4);
        float sa = s1[c], sb = s2[c];
        union { __half2 h2[4]; uint4 q; } A, Bv;
        A.h2[0] = __floats2half2_rn(u0.x * sa, u0.y * sa);
        A.h2[1] = __floats2half2_rn(u0.z * sa, u0.w * sa);
        A.h2[2] = __floats2half2_rn(u1.x * sa, u1.y * sa);
        A.h2[3] = __floats2half2_rn(u1.z * sa, u1.w * sa);
        Bv.h2[0] = __floats2half2_rn(v0.x * sb, v0.y * sb);
        Bv.h2[1] = __floats2half2_rn(v0.z * sb, v0.w * sb);
        Bv.h2[2] = __floats2half2_rn(v1.x * sb, v1.y * sb);
        Bv.h2[3] = __floats2half2_rn(v1.z * sb, v1.w * sb);
        *(uint4*)(xsh + X1OFF + (c << 7) + (r8 << 1)) = A.q;
        *(uint4*)(xsh + (c << 7) + (r8 << 1)) = Bv.q;
    }
    if (tid < 8) *(uint4*)(xsh + 65536 + tid * 16) = make_uint4(0, 0, 0, 0);  // zero row j=512
    __syncthreads();

    int wv = tid >> 6;                     // 0..15
    int lane = tid & 63;
    int g4 = lane >> 4;                    // 4 d-groups per wave
    int l = lane & 15;                     // covers rows 4l..4l+3
    uint32_t baseA = (uint32_t)(X1OFF + (l << 3));
    uint32_t baseB = (uint32_t)(l << 3);
    int dcol = (wv << 2) + g4;             // 0..63 within the 64-d window
    int dbase = gy * (CBP_D / NSPLIT);
    float* orow = out + (size_t)(r_base + (l << 2)) * CBP_D;

    for (int dd = 0; dd < 32; ++dd) {
        int d = dbase + (dd << 6) + dcol;  // block covers contiguous 64-d window per dd
        int o0 = offs[d];
        int n4 = offs[d + 1] - o0;         // multiple of 4, pad entries are zero-product
        const uint4* pl = (const uint4*)(pairs + o0);
        float ac0 = 0.f, ac1 = 0.f, ac2 = 0.f, ac3 = 0.f;
        int nb = n4 >> 2;
        for (int t4 = 0; t4 < nb; ++t4) {
            uint4 pp = pl[t4];
            PROC(pp.x); PROC(pp.y); PROC(pp.z); PROC(pp.w);
        }
        float* o = orow + d;
        o[0] = ac0; o[CBP_D] = ac1; o[2 * CBP_D] = ac2; o[3 * CBP_D] = ac3;
    }
}

// ================= launch =================

extern "C" void kernel_launch(void* const* d_in, const int* in_sizes, int n_in,
                              void* d_out, int out_size, void* d_ws, size_t ws_size,
                              hipStream_t stream) {
    const float* b1 = (const float*)d_in[0];
    const float* b2 = (const float*)d_in[1];
    const int*   h1 = (const int*)d_in[2];
    const float* s1 = (const float*)d_in[3];
    const int*   h2 = (const int*)d_in[4];
    const float* s2 = (const float*)d_in[5];
    float* out = (float*)d_out;

    int* cnt2    = (int*)d_ws;            // 8192
    int* boff    = cnt2 + 8192;           // 8200 (8193 used)
    int* bucket2 = boff + 8200;           // 512
    int* cnt     = bucket2 + 512;         // 8192
    int* offs    = cnt + 8192;            // 8200 (8193 used)
    uint32_t* pairs = (uint32_t*)(offs + 8200);   // <= 262144 + 3*8192

    p1_buckets<<<1, 512, 0, stream>>>(h2, cnt2, boff, bucket2);
    p2_countd <<<64, 128, 0, stream>>>(h1, cnt2, cnt);
    p3_scan_pad<<<1, 1024, 0, stream>>>(cnt, offs);
    p4_fill   <<<64, 128, 0, stream>>>(h1, cnt2, boff, bucket2, offs, pairs);

    dim3 g(CBP_W * 8 / ROWS, NSPLIT);     // (64, 4)
    k_main<<<g, NTHREADS, 0, stream>>>(b1, b2, s1, s2, offs, pairs, out);
}